// Round 4
// baseline (1299.956 us; speedup 1.0000x reference)
//
#include <hip/hip_runtime.h>
#include <hip/hip_bf16.h>

typedef __bf16 bf16x8 __attribute__((ext_vector_type(8)));
typedef float  f32x4  __attribute__((ext_vector_type(4)));

#define DIM    512
#define DINNER 1024
#define SEQL   256
#define BATCH  2
#define NLAYER 7    // layer 7's mixer output is discarded by the reference
#define LPAD   260  // row stride for [.][l] LDS arrays: 260%32==4 -> staggered banks
#define NCH    8    // scan chunks
#define CLEN   32   // steps per chunk
#define NBLK   256  // == CU count; 125KB LDS forces 1 block/CU -> all co-resident
#define NTHR   1024

#define N4WI (NLAYER * 2048 * 512 / 4)
#define N4WX (NLAYER * 64 * 1024 / 4)
#define N4WO (NLAYER * 512 * 1024 / 4)
#define N4ALL (N4WI + N4WX + N4WO)

// ---- device-scope grid barrier: one fresh counter per barrier instance ----
// Counters zeroed by hipMemsetAsync before each launch (same stream, capture-safe).
__device__ __forceinline__ void barwait(unsigned* c) {
  __syncthreads();
  if (threadIdx.x == 0) {
    __threadfence();                       // release: flush this block's writes
    atomicAdd(c, 1u);                      // device-scope by default on HIP
    while (atomicAdd(c, 0u) < NBLK) __builtin_amdgcn_s_sleep(10);
    __threadfence();                       // acquire: invalidate L1/L2 for fresh reads
  }
  __syncthreads();
}

// ---- 32x32 quadrant GEMM over a K-range: C += A[row0..+32, k] * B[col0..+32, k]^T
__device__ __forceinline__ void qgemm32(const __hip_bfloat16* __restrict__ A,
                                        const __hip_bfloat16* __restrict__ B,
                                        int K, int row0, int col0, int kc0, int nkc,
                                        int lane, f32x4 acc[4]) {
  const int r = lane & 15, g = lane >> 4;
  const bf16x8* pa0 = reinterpret_cast<const bf16x8*>(A + (size_t)(row0 + r) * K) + g + kc0 * 4;
  const bf16x8* pa1 = reinterpret_cast<const bf16x8*>(A + (size_t)(row0 + 16 + r) * K) + g + kc0 * 4;
  const bf16x8* pb0 = reinterpret_cast<const bf16x8*>(B + (size_t)(col0 + r) * K) + g + kc0 * 4;
  const bf16x8* pb1 = reinterpret_cast<const bf16x8*>(B + (size_t)(col0 + 16 + r) * K) + g + kc0 * 4;
#pragma unroll 4
  for (int kc = 0; kc < nkc; ++kc) {
    bf16x8 a0 = pa0[kc * 4];
    bf16x8 a1 = pa1[kc * 4];
    bf16x8 b0 = pb0[kc * 4];
    bf16x8 b1 = pb1[kc * 4];
    acc[0] = __builtin_amdgcn_mfma_f32_16x16x32_bf16(a0, b0, acc[0], 0, 0, 0);
    acc[1] = __builtin_amdgcn_mfma_f32_16x16x32_bf16(a0, b1, acc[1], 0, 0, 0);
    acc[2] = __builtin_amdgcn_mfma_f32_16x16x32_bf16(a1, b0, acc[2], 0, 0, 0);
    acc[3] = __builtin_amdgcn_mfma_f32_16x16x32_bf16(a1, b1, acc[3], 0, 0, 0);
  }
}

__global__ __launch_bounds__(NTHR) void k_mega(
    const float* __restrict__ x,   const float* __restrict__ Wi,
    const float* __restrict__ cw,  const float* __restrict__ cb,
    const float* __restrict__ Wx,  const float* __restrict__ Wdt,
    const float* __restrict__ bdt, const float* __restrict__ Alog,
    const float* __restrict__ Dv,  const float* __restrict__ Wo,
    const float* __restrict__ nw,
    float* __restrict__ res, __hip_bfloat16* __restrict__ hn,
    float* __restrict__ xz,  float* __restrict__ xc,
    __hip_bfloat16* __restrict__ xcb, float* __restrict__ dbl,
    __hip_bfloat16* __restrict__ y,
    __hip_bfloat16* __restrict__ wib, __hip_bfloat16* __restrict__ wxb,
    __hip_bfloat16* __restrict__ wob,
    unsigned* __restrict__ bars, float* __restrict__ out) {
  // ---- shared memory (scan layout; s_cp doubles as GEMM split-K reduce buffer) ----
  __shared__ __align__(16) float s_dt[8][LPAD];
  __shared__ __align__(16) float s_xc[8][LPAD];
  __shared__ __align__(16) float s_B[16][LPAD];
  __shared__ __align__(16) float s_C[16][LPAD];
  __shared__ __align__(16) float s_cp[SEQL][68];
  __shared__ float s_pe[NCH][128];
  __shared__ float s_se[NCH][128];
  float* s_red = &s_cp[0][0];               // 16KB needed, 68KB available

  const int tid = threadIdx.x;
  const int bid = blockIdx.x;
  const int wid = tid >> 6;
  const int lane = tid & 63;
  unsigned* bar = bars;

  // ================= S0: weight f32->bf16 casts + input transpose =================
  for (int i = bid * NTHR + tid; i < N4ALL; i += NBLK * NTHR) {
    const float* src; __hip_bfloat16* dst; int j;
    if (i < N4WI)             { src = Wi; dst = wib; j = i; }
    else if (i < N4WI + N4WX) { src = Wx; dst = wxb; j = i - N4WI; }
    else                      { src = Wo; dst = wob; j = i - N4WI - N4WX; }
    float4 v = reinterpret_cast<const float4*>(src)[j];
    struct alignas(8) B4 { __hip_bfloat16 a, b, c, d; };
    B4 o{ (__hip_bfloat16)v.x, (__hip_bfloat16)v.y, (__hip_bfloat16)v.z, (__hip_bfloat16)v.w };
    reinterpret_cast<B4*>(dst)[j] = o;
  }
  {
    int idx = bid * NTHR + tid;             // exactly 262144 threads = B*L*DIM
    int d = idx & (DIM - 1), l = (idx >> 9) & (SEQL - 1), b = idx >> 17;
    res[idx] = x[((size_t)((b << 9) + d) << 8) + l];
  }
  barwait(bar); bar += 16;

  for (int L = 0; L < NLAYER; ++L) {
    const __hip_bfloat16* wi = wib + (size_t)L * 2048 * 512;
    const __hip_bfloat16* wx = wxb + (size_t)L * 64 * 1024;
    const __hip_bfloat16* wo = wob + (size_t)L * 512 * 1024;
    const float* wdt  = Wdt + (size_t)L * DINNER * 32;
    const float* bdtL = bdt + L * DINNER;
    const float* alog = Alog + (size_t)L * DINNER * 16;
    const float* dv   = Dv + L * DINNER;
    const float* nwL  = nw + L * DIM;

    // ================= S1: rmsnorm + bf16 cast (2 rows/block) =================
    if (wid < 2) {
      int row = (bid << 1) + wid;
      const float* rr = res + ((size_t)row << 9);
      float v[8]; float ss = 0.f;
#pragma unroll
      for (int j = 0; j < 8; ++j) { v[j] = rr[lane + (j << 6)]; ss = fmaf(v[j], v[j], ss); }
#pragma unroll
      for (int m = 1; m < 64; m <<= 1) ss += __shfl_xor(ss, m);
      float inv = rsqrtf(ss * (1.0f / 512.0f) + 1e-5f);
      __hip_bfloat16* o = hn + ((size_t)row << 9);
#pragma unroll
      for (int j = 0; j < 8; ++j) o[lane + (j << 6)] = (__hip_bfloat16)(v[j] * inv * nwL[lane + (j << 6)]);
    }
    barwait(bar); bar += 16;

    // ================= S2: in_proj GEMM (64x64 tile/block, 4 quadrant waves) =====
    if (wid < 4) {
      int bx = bid >> 5, by = bid & 31;
      int row0 = bx * 64 + ((wid >> 1) << 5), col0 = by * 64 + ((wid & 1) << 5);
      f32x4 zz = {0.f, 0.f, 0.f, 0.f};
      f32x4 acc[4] = {zz, zz, zz, zz};
      qgemm32(hn, wi, 512, row0, col0, 0, 16, lane, acc);
      const int r = lane & 15, g = lane >> 4;
#pragma unroll
      for (int e = 0; e < 4; ++e) {
        int orow = row0 + ((e >> 1) << 4) + (g << 2);
        int ocol = col0 + ((e & 1) << 4) + r;
#pragma unroll
        for (int j = 0; j < 4; ++j) xz[(size_t)(orow + j) * 2048 + ocol] = acc[e][j];
      }
    }
    barwait(bar); bar += 16;

    // ================= S3: causal depthwise conv(4) + bias + silu ================
    for (int i = bid * NTHR + tid; i < BATCH * SEQL * DINNER; i += NBLK * NTHR) {
      int d = i & (DINNER - 1), l = (i >> 10) & (SEQL - 1), b = i >> 18;
      const float* base = xz + ((size_t)b << 19) + d;
      size_t off = (size_t)l << 11;
      float4 w = reinterpret_cast<const float4*>(cw)[L * DINNER + d];
      float acc = cb[L * DINNER + d];
      acc = fmaf(base[off], w.w, acc);
      if (l >= 1) acc = fmaf(base[off - 2048], w.z, acc);
      if (l >= 2) acc = fmaf(base[off - 4096], w.y, acc);
      if (l >= 3) acc = fmaf(base[off - 6144], w.x, acc);
      float sv = acc / (1.f + __expf(-acc));
      xc[i] = sv;
      xcb[i] = (__hip_bfloat16)sv;
    }
    barwait(bar); bar += 16;

    // ========== S4: x_proj GEMM (32 jobs on blocks 0..31, 4-way split-K) =========
    {
      bool act = bid < 32;
      int job = bid & 31;
      int row0 = (job >> 1) << 5, col0 = (job & 1) << 5;
      if (act && wid < 4) {
        f32x4 zz = {0.f, 0.f, 0.f, 0.f};
        f32x4 acc[4] = {zz, zz, zz, zz};
        qgemm32(xcb, wx, 1024, row0, col0, wid * 8, 8, lane, acc);
        const int r = lane & 15, g = lane >> 4;
        float* sr = s_red + wid * 1024;
#pragma unroll
        for (int e = 0; e < 4; ++e)
#pragma unroll
          for (int j = 0; j < 4; ++j)
            sr[(((e >> 1) << 4) + (g << 2) + j) * 32 + ((e & 1) << 4) + r] = acc[e][j];
      }
      __syncthreads();
      if (act && wid == 0) {
#pragma unroll
        for (int e = 0; e < 16; ++e) {
          int idx = e * 64 + lane, tr = idx >> 5, tc = idx & 31;
          float sum = s_red[idx] + s_red[1024 + idx] + s_red[2048 + idx] + s_red[3072 + idx];
          dbl[(size_t)(row0 + tr) * 64 + col0 + tc] = sum;
        }
      }
    }
    barwait(bar); bar += 16;

    // ================= S5: selective scan (chunked two-pass, whole block) ========
    {
      const int cg = tid >> 7;
      const int tt = tid & 127;
      const int n = tt & 15, dl = tt >> 4;
      const int b = bid >> 7;
      const int d0 = (bid & 127) << 3;
      const int d = d0 + dl;
      const int bL = b * SEQL;
#pragma unroll
      for (int k = 0; k < 4; ++k) {
        int idx = tid + (k << 10);
        int l = idx >> 4, nn = idx & 15;
        const float* row = dbl + ((size_t)(bL + l) << 6);
        s_B[nn][l] = row[32 + nn];
        s_C[nn][l] = row[48 + nn];
      }
#pragma unroll
      for (int k = 0; k < 2; ++k) {
        int idx = tid + (k << 10);
        int l = idx >> 3, dd = idx & 7;
        s_xc[dd][l] = xc[((size_t)(bL + l) << 10) + d0 + dd];
      }
      {
        const int dw = d0 + cg;
        float4 w4[8];
#pragma unroll
        for (int r2 = 0; r2 < 8; ++r2) w4[r2] = reinterpret_cast<const float4*>(wdt + (size_t)dw * 32)[r2];
        const float bd = bdtL[dw];
#pragma unroll
        for (int k = 0; k < 2; ++k) {
          int l = (tt << 1) + k;
          const float4* row = reinterpret_cast<const float4*>(dbl + ((size_t)(bL + l) << 6));
          float acc = bd;
#pragma unroll
          for (int r2 = 0; r2 < 8; ++r2) {
            float4 rv = row[r2];
            acc = fmaf(rv.x, w4[r2].x, acc);
            acc = fmaf(rv.y, w4[r2].y, acc);
            acc = fmaf(rv.z, w4[r2].z, acc);
            acc = fmaf(rv.w, w4[r2].w, acc);
          }
          s_dt[cg][l] = (acc > 20.f) ? acc : log1pf(__expf(acc));
        }
      }
      __syncthreads();

      const float An = -__expf(alog[(size_t)d * 16 + n]);
      const int lb = cg << 5;

      float s = 0.f, P = 1.f;
#pragma unroll 2
      for (int l4 = 0; l4 < CLEN; l4 += 4) {
        const int l = lb + l4;
        float4 dt4 = *reinterpret_cast<const float4*>(&s_dt[dl][l]);
        float4 xc4 = *reinterpret_cast<const float4*>(&s_xc[dl][l]);
        float4 B4  = *reinterpret_cast<const float4*>(&s_B[n][l]);
        float dA;
        dA = __expf(dt4.x * An); P *= dA; s = fmaf(dA, s, dt4.x * xc4.x * B4.x);
        dA = __expf(dt4.y * An); P *= dA; s = fmaf(dA, s, dt4.y * xc4.y * B4.y);
        dA = __expf(dt4.z * An); P *= dA; s = fmaf(dA, s, dt4.z * xc4.z * B4.z);
        dA = __expf(dt4.w * An); P *= dA; s = fmaf(dA, s, dt4.w * xc4.w * B4.w);
      }
      s_pe[cg][tt] = P;
      s_se[cg][tt] = s;
      __syncthreads();

      float ss = 0.f;
      for (int c = 0; c < cg; ++c) ss = fmaf(s_pe[c][tt], ss, s_se[c][tt]);

      float s2 = ss;
#pragma unroll 2
      for (int l4 = 0; l4 < CLEN; l4 += 4) {
        const int l = lb + l4;
        float4 dt4 = *reinterpret_cast<const float4*>(&s_dt[dl][l]);
        float4 xc4 = *reinterpret_cast<const float4*>(&s_xc[dl][l]);
        float4 B4  = *reinterpret_cast<const float4*>(&s_B[n][l]);
        float4 C4  = *reinterpret_cast<const float4*>(&s_C[n][l]);
        float dA, c;
        dA = __expf(dt4.x * An); s2 = fmaf(dA, s2, dt4.x * xc4.x * B4.x); c = s2 * C4.x;
        c += __shfl_xor(c, 1); if (!(n & 1)) s_cp[l + 0][(dl << 3) | (n >> 1)] = c;
        dA = __expf(dt4.y * An); s2 = fmaf(dA, s2, dt4.y * xc4.y * B4.y); c = s2 * C4.y;
        c += __shfl_xor(c, 1); if (!(n & 1)) s_cp[l + 1][(dl << 3) | (n >> 1)] = c;
        dA = __expf(dt4.z * An); s2 = fmaf(dA, s2, dt4.z * xc4.z * B4.z); c = s2 * C4.z;
        c += __shfl_xor(c, 1); if (!(n & 1)) s_cp[l + 2][(dl << 3) | (n >> 1)] = c;
        dA = __expf(dt4.w * An); s2 = fmaf(dA, s2, dt4.w * xc4.w * B4.w); c = s2 * C4.w;
        c += __shfl_xor(c, 1); if (!(n & 1)) s_cp[l + 3][(dl << 3) | (n >> 1)] = c;
      }
      __syncthreads();

#pragma unroll
      for (int k = 0; k < 2; ++k) {
        int idx = tid + (k << 10);
        int l = idx >> 3, dd = idx & 7;
        const float* cr = &s_cp[l][dd << 3];
        float4 a0 = *reinterpret_cast<const float4*>(cr);
        float4 a1 = *reinterpret_cast<const float4*>(cr + 4);
        float sum = ((a0.x + a0.y) + (a0.z + a0.w)) + ((a1.x + a1.y) + (a1.z + a1.w));
        float xcv = s_xc[dd][l];
        float zv = xz[((size_t)(bL + l) << 11) + DINNER + d0 + dd];
        float yv = (sum + dv[d0 + dd] * xcv) * (zv / (1.f + __expf(-zv)));
        y[((size_t)(bL + l) << 10) + d0 + dd] = (__hip_bfloat16)yv;
      }
    }
    barwait(bar); bar += 16;

    // ====== S6: out_proj GEMM += res (64 tiles x 4 quadrants, 4-way split-K) =====
    {
      int tile = bid >> 2, q = bid & 3;
      int bx = tile >> 3, by = tile & 7;
      int row0 = bx * 64 + ((q >> 1) << 5), col0 = by * 64 + ((q & 1) << 5);
      if (wid < 4) {
        f32x4 zz = {0.f, 0.f, 0.f, 0.f};
        f32x4 acc[4] = {zz, zz, zz, zz};
        qgemm32(y, wo, 1024, row0, col0, wid * 8, 8, lane, acc);
        const int r = lane & 15, g = lane >> 4;
        float* sr = s_red + wid * 1024;
#pragma unroll
        for (int e = 0; e < 4; ++e)
#pragma unroll
          for (int j = 0; j < 4; ++j)
            sr[(((e >> 1) << 4) + (g << 2) + j) * 32 + ((e & 1) << 4) + r] = acc[e][j];
      }
      __syncthreads();
      if (wid == 0) {
#pragma unroll
        for (int e = 0; e < 16; ++e) {
          int idx = e * 64 + lane, tr = idx >> 5, tc = idx & 31;
          float sum = s_red[idx] + s_red[1024 + idx] + s_red[2048 + idx] + s_red[3072 + idx];
          res[(size_t)(row0 + tr) * 512 + col0 + tc] += sum;
        }
      }
    }
    barwait(bar); bar += 16;
  }

  // ================= final: transpose out[b][c][l] = res[b][l][c] =================
  {
    int idx = bid * NTHR + tid;             // exactly 262144
    int l = idx & (SEQL - 1), c = (idx >> 8) & (DIM - 1), b = idx >> 17;
    out[idx] = res[((size_t)((b << 8) + l) << 9) + c];
  }
}

// ---------------- launcher ----------------
extern "C" void kernel_launch(void* const* d_in, const int* in_sizes, int n_in,
                              void* d_out, int out_size, void* d_ws, size_t ws_size,
                              hipStream_t stream) {
  (void)in_sizes; (void)n_in; (void)out_size; (void)ws_size;
  const float* x    = (const float*)d_in[0];
  const float* Wi   = (const float*)d_in[1];
  const float* cw   = (const float*)d_in[2];
  const float* cb   = (const float*)d_in[3];
  const float* Wx   = (const float*)d_in[4];
  const float* Wdt  = (const float*)d_in[5];
  const float* bdt  = (const float*)d_in[6];
  const float* Alog = (const float*)d_in[7];
  const float* Dv   = (const float*)d_in[8];
  const float* Wo   = (const float*)d_in[9];
  const float* nw   = (const float*)d_in[10];

  char* ws = (char*)d_ws;
  float*          res = (float*)(ws + 0);                   // 1 MB
  __hip_bfloat16* hn  = (__hip_bfloat16*)(ws + 1048576);    // 0.5 MB
  float*          xz  = (float*)(ws + 1572864);             // 4 MB
  float*          xc  = (float*)(ws + 5767168);             // 2 MB
  __hip_bfloat16* xcb = (__hip_bfloat16*)(ws + 7864320);    // 1 MB
  float*          dbl = (float*)(ws + 8912896);             // 128 KB
  __hip_bfloat16* y   = (__hip_bfloat16*)(ws + 9043968);    // 1 MB
  __hip_bfloat16* wib = (__hip_bfloat16*)(ws + 10092544);   // 14 MB
  __hip_bfloat16* wxb = (__hip_bfloat16*)(ws + 24772608);   // 0.9 MB
  __hip_bfloat16* wob = (__hip_bfloat16*)(ws + 25690112);   // 7 MB
  unsigned*       bars = (unsigned*)(ws + 41943040);        // 43 barriers x 64B

  hipMemsetAsync(bars, 0, 4096, stream);
  k_mega<<<NBLK, NTHR, 0, stream>>>(x, Wi, cw, cb, Wx, Wdt, bdt, Alog, Dv, Wo, nw,
                                    res, hn, xz, xc, xcb, dbl, y, wib, wxb, wob,
                                    bars, (float*)d_out);
}